// Round 1
// baseline (3169.939 us; speedup 1.0000x reference)
//
#include <hip/hip_runtime.h>
#include <math.h>

// ---------------------------------------------------------------------------
// AttentionAggregation: scores = tanh(x@W1+b1)@W2+b2 ; segmented softmax over
// sorted batch_idx ; out = segment_sum(x * alpha) ; returns (out, alpha).
// N=2e6, D_IN=D_HID=128, NUM_SEG=4096 (derived at runtime from sizes).
// ---------------------------------------------------------------------------

#define CHUNK 2048

// XOR-swizzled transposed-x LDS layout: element (k, r) of the 128x128 tile.
// Preserves 4-float contiguity (low 2 bits of r) so float4 reads stay aligned;
// swizzling r's quad index by (k>>2)&7 breaks the 32-way transpose-write
// conflict down to ~4-way and keeps the k-loop reads conflict-free.
#define XIDX(k, r) ((k)*128 + (((((r) >> 2) ^ (((k) >> 2) & 7)) << 2) | ((r) & 3)))

// Monotone float<->int encoding so integer atomicMax implements float max.
__device__ __forceinline__ int enc_f(float f) {
  int b = __float_as_int(f);
  return b < 0 ? (b ^ 0x7fffffff) : b;
}
__device__ __forceinline__ float dec_f(int v) {
  return __int_as_float(v < 0 ? (v ^ 0x7fffffff) : v);
}

__global__ void k_init(float* __restrict__ outG, float* __restrict__ segsum,
                       int* __restrict__ segmax, int nseg) {
  int i = blockIdx.x * blockDim.x + threadIdx.x;
  if (i < nseg * 128) outG[i] = 0.0f;
  if (i < nseg) {
    segsum[i] = 0.0f;
    segmax[i] = (int)0x80000000;  // enc(-inf) lower bound; every used seg is non-empty
  }
}

// One 128-row tile per block. 256 threads, 8x8 fp32 micro-tile per thread.
// LDS: W1 64KB + swizzled x^T 64KB + reduction scratch ~9KB = ~141KB -> 1 block/CU.
__launch_bounds__(256, 1)
__global__ void k_score(const float* __restrict__ x, const float* __restrict__ W1,
                        const float* __restrict__ b1, const float* __restrict__ W2,
                        const float* __restrict__ b2, float* __restrict__ sOut, int N) {
  __shared__ float wS[128 * 128];
  __shared__ float xTS[128 * 128];
  __shared__ float b1S[128];
  __shared__ float w2S[128];
  __shared__ float sred[128 * 17];  // stride 17 breaks 16-way write conflict

  const int t = threadIdx.x;
  const int rowBase = blockIdx.x << 7;

  // Stage W1 linearly (coalesced float4 both sides).
  {
    const float4* Wg = (const float4*)W1;
    float4* Ws = (float4*)wS;
#pragma unroll
    for (int j = 0; j < 16; ++j) Ws[t + 256 * j] = Wg[t + 256 * j];
  }
  if (t < 128) {
    b1S[t] = b1[t];
    w2S[t] = W2[t];
  }

  // Stage x tile transposed+swizzled. Global: 32 lanes read one row's 128
  // floats contiguously (coalesced). LDS: 4 scalar writes/thread, ~4-way.
#pragma unroll
  for (int j = 0; j < 16; ++j) {
    int q = t + 256 * j;  // 0..4095 float4 quads
    int row = q >> 5;     // 0..127
    int kq = q & 31;      // 0..31
    int gr = rowBase + row;
    float4 v = make_float4(0.f, 0.f, 0.f, 0.f);
    if (gr < N) v = *(const float4*)(x + (size_t)gr * 128 + 4 * kq);
    int k0 = kq * 4;
    xTS[XIDX(k0 + 0, row)] = v.x;
    xTS[XIDX(k0 + 1, row)] = v.y;
    xTS[XIDX(k0 + 2, row)] = v.z;
    xTS[XIDX(k0 + 3, row)] = v.w;
  }
  __syncthreads();

  // Thread map: rg = t&15 (16 distinct rows-groups per wave -> 2-way-free
  // swizzled a-reads), cg = t>>4 (4 distinct col-groups per wave -> b-reads
  // are 4-address broadcasts).
  const int rg = t & 15, cg = t >> 4;
  const int r0 = rg * 8, c0 = cg * 8;

  float acc[8][8];
#pragma unroll
  for (int i = 0; i < 8; ++i)
#pragma unroll
    for (int j = 0; j < 8; ++j) acc[i][j] = 0.f;

#pragma unroll 4
  for (int k = 0; k < 128; ++k) {
    const int f = (k >> 2) & 7;
    float a_[8], b_[8];
    *(float4*)&a_[0] = *(const float4*)&xTS[k * 128 + (((2 * rg) ^ f) << 2)];
    *(float4*)&a_[4] = *(const float4*)&xTS[k * 128 + (((2 * rg + 1) ^ f) << 2)];
    *(float4*)&b_[0] = *(const float4*)&wS[k * 128 + c0];
    *(float4*)&b_[4] = *(const float4*)&wS[k * 128 + c0 + 4];
#pragma unroll
    for (int i = 0; i < 8; ++i)
#pragma unroll
      for (int j = 0; j < 8; ++j) acc[i][j] = fmaf(a_[i], b_[j], acc[i][j]);
  }

  // Epilogue: h = tanh(acc + b1), partial s = h . W2 over this thread's cols.
  const float bb2 = b2[0];
#pragma unroll
  for (int i = 0; i < 8; ++i) {
    float p = 0.f;
#pragma unroll
    for (int j = 0; j < 8; ++j) {
      float h = tanhf(acc[i][j] + b1S[c0 + j]);
      p = fmaf(h, w2S[c0 + j], p);
    }
    sred[(r0 + i) * 17 + cg] = p;
  }
  __syncthreads();
  if (t < 128) {
    float sv = bb2;
#pragma unroll
    for (int j = 0; j < 16; ++j) sv += sred[t * 17 + j];
    int gr = rowBase + t;
    if (gr < N) sOut[gr] = sv;
  }
}

// Segment max: sorted idx -> most waves are segment-uniform: butterfly
// reduce then a single int-encoded atomicMax per wave.
__global__ void k_segmax(const float* __restrict__ s, const int* __restrict__ idx,
                         int* __restrict__ segmax, int N) {
  int i = blockIdx.x * 256 + threadIdx.x;
  bool valid = i < N;
  int g = 0;
  float v = -INFINITY;
  if (valid) {
    g = idx[i];
    v = s[i];
  }
  bool fullblock = (blockIdx.x * 256 + 255) < N;
  int g0 = __shfl(g, 0);
  int g63 = __shfl(g, 63);
  if (fullblock && g0 == g63) {  // sorted => whole wave same segment
#pragma unroll
    for (int off = 32; off > 0; off >>= 1) v = fmaxf(v, __shfl_xor(v, off));
    if ((threadIdx.x & 63) == 0) atomicMax(&segmax[g], enc_f(v));
  } else if (valid) {
    atomicMax(&segmax[g], enc_f(v));
  }
}

// Segment sum of e = exp(s - segmax[idx]).
__global__ void k_segsum(const float* __restrict__ s, const int* __restrict__ idx,
                         const int* __restrict__ segmax, float* __restrict__ segsum,
                         int N) {
  int i = blockIdx.x * 256 + threadIdx.x;
  bool valid = i < N;
  int g = 0;
  float e = 0.f;
  if (valid) {
    g = idx[i];
    e = expf(s[i] - dec_f(segmax[g]));
  }
  bool fullblock = (blockIdx.x * 256 + 255) < N;
  int g0 = __shfl(g, 0);
  int g63 = __shfl(g, 63);
  if (fullblock && g0 == g63) {
#pragma unroll
    for (int off = 32; off > 0; off >>= 1) e += __shfl_xor(e, off);
    if ((threadIdx.x & 63) == 0) atomicAdd(&segsum[g], e);
  } else if (valid) {
    atomicAdd(&segsum[g], e);
  }
}

// Per 2048-row chunk: compute+write alpha (staged in LDS), then run-length
// accumulate alpha*x per segment with float4 column groups; one atomic flush
// per segment boundary per thread (sorted idx => ~5 flushes/thread).
__global__ void k_alpha_out(const float* __restrict__ x, const float* __restrict__ s,
                            const int* __restrict__ idx, const int* __restrict__ segmax,
                            const float* __restrict__ segsum, float* __restrict__ outG,
                            float* __restrict__ alphaOut, int N) {
  __shared__ float alphaS[CHUNK];
  __shared__ int idxS[CHUNK];
  const int t = threadIdx.x;
  const int base = blockIdx.x * CHUNK;

#pragma unroll
  for (int j = 0; j < CHUNK; j += 256) {
    int i = base + j + t;
    if (i < N) {
      int g = idx[i];
      float m = dec_f(segmax[g]);
      float a = expf(s[i] - m) / (segsum[g] + 1e-16f);
      alphaS[j + t] = a;
      idxS[j + t] = g;
      alphaOut[i] = a;
    }
  }
  __syncthreads();

  const int cgr = t & 31;  // 4-float column group: cols 4*cgr .. 4*cgr+3
  const int so = t >> 5;   // row phase 0..7
  float4 acc = make_float4(0.f, 0.f, 0.f, 0.f);
  int gprev = -1;
  for (int r = 0; r < CHUNK / 8; ++r) {
    int loc = 8 * r + so;
    int i = base + loc;
    if (i >= N) break;
    int g = idxS[loc];
    if (g != gprev) {
      if (gprev >= 0) {
        float* o = outG + (size_t)gprev * 128 + 4 * cgr;
        atomicAdd(o + 0, acc.x);
        atomicAdd(o + 1, acc.y);
        atomicAdd(o + 2, acc.z);
        atomicAdd(o + 3, acc.w);
      }
      acc = make_float4(0.f, 0.f, 0.f, 0.f);
      gprev = g;
    }
    float a = alphaS[loc];
    const float4 xv = *(const float4*)(x + (size_t)i * 128 + 4 * cgr);
    acc.x = fmaf(a, xv.x, acc.x);
    acc.y = fmaf(a, xv.y, acc.y);
    acc.z = fmaf(a, xv.z, acc.z);
    acc.w = fmaf(a, xv.w, acc.w);
  }
  if (gprev >= 0) {
    float* o = outG + (size_t)gprev * 128 + 4 * cgr;
    atomicAdd(o + 0, acc.x);
    atomicAdd(o + 1, acc.y);
    atomicAdd(o + 2, acc.z);
    atomicAdd(o + 3, acc.w);
  }
}

extern "C" void kernel_launch(void* const* d_in, const int* in_sizes, int n_in,
                              void* d_out, int out_size, void* d_ws, size_t ws_size,
                              hipStream_t stream) {
  const float* x = (const float*)d_in[0];
  const float* W1 = (const float*)d_in[1];
  const float* b1 = (const float*)d_in[2];
  const float* W2 = (const float*)d_in[3];
  const float* b2 = (const float*)d_in[4];
  const int* idx = (const int*)d_in[5];

  const int N = in_sizes[5];
  const int nseg = (out_size - N) / 128;

  float* outG = (float*)d_out;
  float* alphaOut = (float*)d_out + (size_t)nseg * 128;

  float* sBuf = (float*)d_ws;
  int* segmax = (int*)((char*)d_ws + (size_t)N * 4);
  float* segsum = (float*)((char*)d_ws + (size_t)N * 4 + (size_t)nseg * 4);

  int initBlocks = (nseg * 128 + 255) / 256;
  k_init<<<initBlocks, 256, 0, stream>>>(outG, segsum, segmax, nseg);

  int nTiles = (N + 127) / 128;
  k_score<<<nTiles, 256, 0, stream>>>(x, W1, b1, W2, b2, sBuf, N);

  int nB = (N + 255) / 256;
  k_segmax<<<nB, 256, 0, stream>>>(sBuf, idx, segmax, N);
  k_segsum<<<nB, 256, 0, stream>>>(sBuf, idx, segmax, segsum, N);

  int nC = (N + CHUNK - 1) / CHUNK;
  k_alpha_out<<<nC, 256, 0, stream>>>(x, sBuf, idx, segmax, segsum, outG, alphaOut, N);
}